// Round 9
// baseline (502.221 us; speedup 1.0000x reference)
//
#include <hip/hip_runtime.h>
#include <cstdint>
#include <cstddef>

typedef __attribute__((ext_vector_type(8))) short frag8;
typedef __attribute__((ext_vector_type(4))) float f32x4;

static __device__ __forceinline__ unsigned short f2bf_r(float f) {
    return (unsigned short)((__float_as_uint(f) + 0x8000u) >> 16);   // round-half-up
}

// async global->LDS, 16B per lane. LDS dest = wave-uniform base + lane*16.
static __device__ __forceinline__ void gll16(const void* g, void* l) {
    __builtin_amdgcn_global_load_lds(
        (const __attribute__((address_space(1))) unsigned int*)g,
        (__attribute__((address_space(3))) unsigned int*)l, 16, 0, 0);
}

// ---------------- fused MLP: out = relu(X@W1+b1)@W2' + b2' ----------------------
// R1 version verbatim (replay-proven 4x).
__global__ __launch_bounds__(256, 2)
void mlp_fused(const float* __restrict__ X0, const float* __restrict__ X1,
               const unsigned short* __restrict__ W1T0, const unsigned short* __restrict__ W1T1,
               const float* __restrict__ b1v0, const float* __restrict__ b1v1,
               const unsigned short* __restrict__ W2T0, const unsigned short* __restrict__ W2T1,
               const float* __restrict__ b2v0, const float* __restrict__ b2v1,
               unsigned short* __restrict__ O0, unsigned short* __restrict__ O1)
{
    __shared__ __align__(16) unsigned short As[64 * 72];     // 9216 B (fp32-staged A, pad 72)
    __shared__ __align__(16) unsigned short Bs[256 * 64];    // 32768 B (weight tile, swizzled)
    __shared__ __align__(16) unsigned short hs[64 * 264];    // 33792 B (h tile / C-stage)

    const int mod = blockIdx.y;
    const float* X = mod ? X1 : X0;
    const unsigned short* W1T = mod ? W1T1 : W1T0;
    const unsigned short* W2T = mod ? W2T1 : W2T0;
    const float* b1 = mod ? b1v1 : b1v0;
    const float* b2 = mod ? b2v1 : b2v0;
    unsigned short* O = mod ? O1 : O0;

    const int t    = threadIdx.x;
    const int wave = t >> 6;
    const int lane = t & 63;
    const int quad = lane >> 4;
    const int l15  = lane & 15;
    const int m0   = blockIdx.x * 64;

    const int rowB = lane >> 3;                 // 0..7
    const int qB   = (lane & 7) ^ rowB;
    const int nRowBase = wave * 64 + rowB;      // +p*8 per call
    unsigned short* BsW = Bs + wave * 4096;     // 8 calls x 512 ush
    const int swz = l15 & 7;

    f32x4 acc[4][4];
    #pragma unroll
    for (int i = 0; i < 4; ++i)
        #pragma unroll
        for (int j = 0; j < 4; ++j)
            acc[i][j] = (f32x4){0.f, 0.f, 0.f, 0.f};

    // ---------------- phase 1: h = relu(X@W1+b1), K=512, BK=64 ----------------
    for (int k0 = 0; k0 < 512; k0 += 64) {
        #pragma unroll
        for (int p = 0; p < 4; ++p) {           // stage A 64x64 fp32 -> bf16
            const int idx = p * 256 + t;
            const int row = idx >> 4;
            const int col = (idx & 15) * 4;
            const float4 v = *(const float4*)(X + (size_t)(m0 + row) * 512 + k0 + col);
            const unsigned int a0 = __float_as_uint(v.x) + 0x8000u;
            const unsigned int a1 = __float_as_uint(v.y) + 0x8000u;
            const unsigned int a2 = __float_as_uint(v.z) + 0x8000u;
            const unsigned int a3 = __float_as_uint(v.w) + 0x8000u;
            uint2 pk;
            pk.x = __builtin_amdgcn_perm(a1, a0, 0x07060302u);
            pk.y = __builtin_amdgcn_perm(a3, a2, 0x07060302u);
            *(uint2*)&As[row * 72 + col] = pk;
        }
        #pragma unroll
        for (int p = 0; p < 8; ++p)             // stage W1T 256x64 bf16
            gll16(W1T + (size_t)(nRowBase + p * 8) * 512 + qB * 8 + k0, BsW + p * 512);
        __syncthreads();

        frag8 af[2][4], bf[2][4];
        #pragma unroll
        for (int i = 0; i < 4; ++i)
            #pragma unroll
            for (int kh = 0; kh < 2; ++kh)
                af[kh][i] = *(const frag8*)&As[(i * 16 + l15) * 72 + kh * 32 + quad * 8];
        #pragma unroll
        for (int j = 0; j < 4; ++j) {
            const int row = wave * 64 + j * 16 + l15;
            #pragma unroll
            for (int kh = 0; kh < 2; ++kh)
                bf[kh][j] = *(const frag8*)&Bs[row * 64 + (((kh * 4 + quad) ^ swz) * 8)];
        }
        #pragma unroll
        for (int kh = 0; kh < 2; ++kh)
            #pragma unroll
            for (int i = 0; i < 4; ++i)
                #pragma unroll
                for (int j = 0; j < 4; ++j)
                    acc[i][j] = __builtin_amdgcn_mfma_f32_16x16x32_bf16(af[kh][i], bf[kh][j], acc[i][j], 0, 0, 0);
        __syncthreads();
    }

    // h -> LDS (bias + relu + bf16), C-layout scatter
    #pragma unroll
    for (int j = 0; j < 4; ++j) {
        const int col = wave * 64 + j * 16 + l15;
        const float bv = b1[col];
        #pragma unroll
        for (int i = 0; i < 4; ++i) {
            const int rl = i * 16 + quad * 4;
            #pragma unroll
            for (int r = 0; r < 4; ++r)
                hs[(rl + r) * 264 + col] = f2bf_r(fmaxf(acc[i][j][r] + bv, 0.0f));
        }
    }
    __syncthreads();

    // ---------------- phase 2: out = h@W2' + b2', K=256, BK=64 ----------------
    #pragma unroll
    for (int i = 0; i < 4; ++i)
        #pragma unroll
        for (int j = 0; j < 4; ++j)
            acc[i][j] = (f32x4){0.f, 0.f, 0.f, 0.f};

    for (int k0 = 0; k0 < 256; k0 += 64) {
        #pragma unroll
        for (int p = 0; p < 8; ++p)
            gll16(W2T + (size_t)(nRowBase + p * 8) * 256 + qB * 8 + k0, BsW + p * 512);
        __syncthreads();

        frag8 af[2][4], bf[2][4];
        #pragma unroll
        for (int i = 0; i < 4; ++i)
            #pragma unroll
            for (int kh = 0; kh < 2; ++kh)
                af[kh][i] = *(const frag8*)&hs[(i * 16 + l15) * 264 + k0 + kh * 32 + quad * 8];
        #pragma unroll
        for (int j = 0; j < 4; ++j) {
            const int row = wave * 64 + j * 16 + l15;
            #pragma unroll
            for (int kh = 0; kh < 2; ++kh)
                bf[kh][j] = *(const frag8*)&Bs[row * 64 + (((kh * 4 + quad) ^ swz) * 8)];
        }
        #pragma unroll
        for (int kh = 0; kh < 2; ++kh)
            #pragma unroll
            for (int i = 0; i < 4; ++i)
                #pragma unroll
                for (int j = 0; j < 4; ++j)
                    acc[i][j] = __builtin_amdgcn_mfma_f32_16x16x32_bf16(af[kh][i], bf[kh][j], acc[i][j], 0, 0, 0);
        __syncthreads();
    }

    // out epilogue: bias + bf16 -> hs C-stage -> coalesced 16B stores
    #pragma unroll
    for (int j = 0; j < 4; ++j) {
        const int col = wave * 64 + j * 16 + l15;
        const float bv = b2[col];
        #pragma unroll
        for (int i = 0; i < 4; ++i) {
            const int rl = i * 16 + quad * 4;
            #pragma unroll
            for (int r = 0; r < 4; ++r)
                hs[(rl + r) * 264 + col] = f2bf_r(acc[i][j][r] + bv);
        }
    }
    __syncthreads();
    #pragma unroll
    for (int u = 0; u < 8; ++u) {
        const int chunk = u * 256 + t;          // 0..2047 16B chunks
        const int row = chunk >> 5;
        const int c16 = (chunk & 31) * 8;
        uint4 v = *(const uint4*)&hs[row * 264 + c16];
        *(uint4*)&O[(size_t)(m0 + row) * 256 + c16] = v;
    }
}

// ---------------- lag correlation GEMM v5: 256x128 tile, 2 blocks/CU --------------
// R4's cross-block overlap theory with the register arithmetic FIXED: 8 waves of
// 64x64 (4Mx2N) => acc[4][4] = 64 VGPR; peak ~110 <= 128 => __launch_bounds__(512,4)
// gives an honest 2 blocks/CU (16 waves). One block's LDS-read phase overlaps the
// other's MFMA phase (m114 co-scheduling) -- the measured serial-pipe bottleneck.
// LDS 48 KiB: 2-slot ring x (A 256x32 = 16K + B 128x32 = 8K).
// Sync skeleton = R4-hi's 2-slot ring (hardware-passed correctness+replay in R4),
// parameters re-derived: 3 gll16/wave/tile; stage tile t+1 into slot (t+1)&1 (its
// last reads, tile t-1, closed before the previous closing barrier); vmcnt(3)
// (6 outstanding -> tile t's 3 retired, landed own-wave); barrier -> cross-wave
// visible; never drains to 0 mid-loop; vmcnt(0) at end.
// Grid (4,2,63) = 504 blocks = exactly 2/CU on 252 CUs: single round, no tail.
// Same zp = d*7+s partial layout as sc=7 -> reduce_max unchanged.
// Addressing = the six-round-proven row-pair-XOR swizzle (same formulas; only the
// wave row-bases differ) -> conflicts stay 0.
__global__ __launch_bounds__(512, 4)
void gemm_corr_b(const unsigned short* __restrict__ A, const unsigned short* __restrict__ B,
                 float* __restrict__ partial)
{
    __shared__ __align__(16) unsigned short lds[2 * 12288];  // 2 slots x (A 8192 + B 4096) ush

    const int t    = threadIdx.x;
    const int wave = t >> 6;
    const int lane = t & 63;
    const int quad = lane >> 4;
    const int l15  = lane & 15;
    const int wm   = wave >> 1;          // 0..3 (M quarter, 64 rows)
    const int wn   = wave & 1;           // 0..1 (N half, 64 cols)

    // XCD swizzle: 504 blocks = 8 chunks x 63. logical ell = ((s*9+d)*2 + y)*4 + x
    // -> 8 consecutive ell (one (d,s) group's xy-blocks) land on one XCD chunk.
    const int L   = blockIdx.x + (blockIdx.y << 2) + (blockIdx.z << 3);  // 0..503
    const int ell = (L & 7) * 63 + (L >> 3);
    const int bx   = ell & 3;            // n-tile 0..3
    const int by   = (ell >> 2) & 1;     // m-tile 0..1
    const int rest = ell >> 3;           // 0..62 = s*9 + d
    const int d    = rest % 9;
    const int s    = rest / 9;           // 0..6
    const int m0   = by * 256;
    const int n0   = bx * 128;

    const int nT = (s == 6) ? 136 : 148; // 6*148 + 136 = 1024 tiles; all even
    const int t0 = s * 148;
    const int zp     = d * 7 + s;        // partial slice index (matches reduce_max sc=7)
    const int delta  = d - 4;
    const int kStart = t0 * 32;
    const int koff   = (32768 - 256 * delta) & 32767;

    // staging source mapping (proven): LDS linear lane*16; global src granule
    // pre-swizzled so LDS(rp, g) holds src granule g ^ (rp&7).
    const int gsrc      = (lane & 7) ^ ((lane >> 3) & 7);
    const int srcRowOff = ((lane >> 3) << 1) + (gsrc >> 2);
    const int srcCol    = (gsrc & 3) << 3;
    const size_t aSrcBase = (size_t)(m0 + srcRowOff) * 32768 + srcCol;
    const size_t bSrcBase = (size_t)(n0 + srcRowOff) * 32768 + srcCol;

    // ds_read offsets (shorts): frag row r -> rp=r>>1, g_log=(r&1)*4+quad,
    // g_phys = g_log ^ (rp&7); rp-slot stride 64 shorts; i/j stride 512.
    const int gphys = (((l15 & 1) << 2) | quad) ^ ((l15 >> 1) & 7);
    const int aOff  = (wm * 32 + (l15 >> 1)) * 64 + gphys * 8;
    const int bOff  = (wn * 32 + (l15 >> 1)) * 64 + gphys * 8;

    f32x4 acc[4][4];
    #pragma unroll
    for (int i = 0; i < 4; ++i)
        #pragma unroll
        for (int j = 0; j < 4; ++j)
            acc[i][j] = (f32x4){0.f, 0.f, 0.f, 0.f};

    // prologue: stage tile 0 into slot 0 (3 gll16 per wave: 2 A-chunks + 1 B-chunk)
    {
        const int kk = kStart & 32767;
        const int kb = (kk + koff) & 32767;
        #pragma unroll
        for (int qq = 0; qq < 2; ++qq) {
            const int c = wave * 2 + qq;     // A chunk 0..15 (16 rows = 1 KiB each)
            gll16(A + aSrcBase + (size_t)c * 16 * 32768 + kk, &lds[c * 512]);
        }
        gll16(B + bSrcBase + (size_t)wave * 16 * 32768 + kb, &lds[8192 + wave * 512]);
    }

    for (int kt0 = 0; kt0 < nT; kt0 += 2) {     // nT always even
        #pragma unroll
        for (int u = 0; u < 2; ++u) {
            // stage tile kt0+u+1 -> slot (u+1)&1 (tile kt0+u-1's reads closed at the
            // previous closing barrier). Beyond-slice prefetch wraps &32767: unused.
            {
                const int kk = (kStart + (kt0 + u + 1) * 32) & 32767;
                const int kb = (kk + koff) & 32767;
                unsigned short* LS = &lds[((u + 1) & 1) * 12288];
                #pragma unroll
                for (int qq = 0; qq < 2; ++qq) {
                    const int c = wave * 2 + qq;
                    gll16(A + aSrcBase + (size_t)c * 16 * 32768 + kk, LS + c * 512);
                }
                gll16(B + bSrcBase + (size_t)wave * 16 * 32768 + kb, LS + 8192 + wave * 512);
            }
            // 6 outstanding (tiles t, t+1); <=3 => tile t fully landed own-wave.
            asm volatile("s_waitcnt vmcnt(3)" ::: "memory");
            __builtin_amdgcn_s_barrier();       // cross-wave visibility of DMA writes
            asm volatile("" ::: "memory");

            const unsigned short* LA = &lds[u * 12288];
            const unsigned short* LB = LA + 8192;
            frag8 bf[4];
            #pragma unroll
            for (int j = 0; j < 4; ++j) bf[j] = *(const frag8*)(LB + bOff + j * 512);
            __builtin_amdgcn_s_setprio(1);
            #pragma unroll
            for (int i = 0; i < 4; ++i) {       // af one frag at a time: low liveness
                const frag8 afi = *(const frag8*)(LA + aOff + i * 512);
                #pragma unroll
                for (int j = 0; j < 4; ++j)
                    acc[i][j] = __builtin_amdgcn_mfma_f32_16x16x32_bf16(afi, bf[j], acc[i][j], 0, 0, 0);
            }
            __builtin_amdgcn_s_setprio(0);
            asm volatile("" ::: "memory");
            __builtin_amdgcn_s_barrier();       // protect tile t's reads from next stage
        }
    }
    // drain dangling prefetch DMAs before endpgm (LDS gets reassigned)
    asm volatile("s_waitcnt vmcnt(0)" ::: "memory");

    float* C = partial + ((size_t)zp << 18);
    #pragma unroll
    for (int i = 0; i < 4; ++i) {
        const int rg = m0 + wm * 64 + i * 16 + quad * 4;
        #pragma unroll
        for (int j = 0; j < 4; ++j) {
            const int cg = n0 + wn * 64 + j * 16 + l15;
            #pragma unroll
            for (int r = 0; r < 4; ++r)
                C[(size_t)(rg + r) * 512 + cg] = acc[i][j][r];
        }
    }
}

// ---------------- lag correlation GEMM (R8 verbatim) — small-ws fallback ----------
__global__ __launch_bounds__(512, 2)
void gemm_corr(const unsigned short* __restrict__ A, const unsigned short* __restrict__ B,
               float* __restrict__ partial, int sc)
{
    __shared__ __align__(16) unsigned short lds[4 * 2 * 8192];  // 4 slots x (A,B) x 16 KiB

    const int t    = threadIdx.x;
    const int wave = t >> 6;
    const int lane = t & 63;
    const int quad = lane >> 4;
    const int l15  = lane & 15;
    const int wr   = wave >> 2;          // 0..1  (M half)
    const int wc   = wave & 3;           // 0..3  (N quarter)

    const int L = blockIdx.x + (blockIdx.y << 1) + (blockIdx.z << 2);
    int ell;
    if (sc == 7) {
        const int xcd = L & 7, off = L >> 3;
        ell = (xcd < 4 ? xcd * 32 : 128 + (xcd - 4) * 31) + off;
    } else {
        const int xcd = L & 7, off = L >> 3;
        ell = xcd * 18 + off;
    }
    const int bx   = ell & 1;
    const int by   = (ell >> 1) & 1;
    const int rest = ell >> 2;
    const int d    = rest % 9;
    const int s    = rest / 9;
    const int m0   = by * 256;
    const int n0   = bx * 256;

    int t0, nT;
    if (sc == 7) { nT = (s == 6) ? 136 : 148; t0 = s * 148; }
    else         { nT = 256;                  t0 = s << 8; }
    const int zp     = d * sc + s;
    const int delta  = d - 4;
    const int kStart = t0 * 32;
    const int koff   = (32768 - 256 * delta) & 32767;

    const int gsrc      = (lane & 7) ^ ((lane >> 3) & 7);
    const int srcRowOff = ((lane >> 3) << 1) + (gsrc >> 2);
    const int srcCol    = (gsrc & 3) << 3;
    const size_t aSrcBase = (size_t)(m0 + srcRowOff) * 32768 + srcCol;
    const size_t bSrcBase = (size_t)(n0 + srcRowOff) * 32768 + srcCol;

    const int gphys = (((l15 & 1) << 2) | quad) ^ ((l15 >> 1) & 7);
    const int aOff  = (wr * 64 + (l15 >> 1)) * 64 + gphys * 8;
    const int bOff  = (wc * 32 + (l15 >> 1)) * 64 + gphys * 8;

    f32x4 acc[8][4];
    #pragma unroll
    for (int i = 0; i < 8; ++i)
        #pragma unroll
        for (int j = 0; j < 4; ++j)
            acc[i][j] = (f32x4){0.f, 0.f, 0.f, 0.f};

    frag8 bfb[2][4];

    #pragma unroll
    for (int pt = 0; pt < 3; ++pt) {
        const int kk = (kStart + pt * 32) & 32767;
        const int kb = (kk + koff) & 32767;
        #pragma unroll
        for (int qq = 0; qq < 2; ++qq) {
            const int c = wave * 2 + qq;
            gll16(A + aSrcBase + (size_t)c * 16 * 32768 + kk, &lds[pt * 16384 + c * 512]);
            gll16(B + bSrcBase + (size_t)c * 16 * 32768 + kb, &lds[pt * 16384 + 8192 + c * 512]);
        }
    }
    asm volatile("s_waitcnt vmcnt(8)" ::: "memory");
    __builtin_amdgcn_s_barrier();
    asm volatile("" ::: "memory");
    #pragma unroll
    for (int j = 0; j < 4; ++j)
        bfb[0][j] = *(const frag8*)(&lds[8192] + bOff + j * 512);

    for (int kt0 = 0; kt0 < nT; kt0 += 4) {
        #pragma unroll
        for (int u = 0; u < 4; ++u) {
            {
                const int kk = (kStart + (kt0 + u + 3) * 32) & 32767;
                const int kb = (kk + koff) & 32767;
                unsigned short* LSa = &lds[((u + 3) & 3) * 16384 + wave * 1024];
                unsigned short* LSb = LSa + 8192;
                #pragma unroll
                for (int qq = 0; qq < 2; ++qq) {
                    const int c = wave * 2 + qq;
                    gll16(A + aSrcBase + (size_t)c * 16 * 32768 + kk, LSa + qq * 512);
                    gll16(B + bSrcBase + (size_t)c * 16 * 32768 + kb, LSb + qq * 512);
                }
            }
            asm volatile("s_waitcnt vmcnt(8)" ::: "memory");
            __builtin_amdgcn_s_barrier();
            asm volatile("" ::: "memory");

            const unsigned short* LA  = &lds[u * 16384];
            const unsigned short* LBn = &lds[((u + 1) & 3) * 16384 + 8192];
            frag8 af[8];
            #pragma unroll
            for (int i = 0; i < 4; ++i) af[i] = *(const frag8*)(LA + aOff + i * 512);
            __builtin_amdgcn_s_setprio(1);
            #pragma unroll
            for (int i = 0; i < 4; ++i)
                #pragma unroll
                for (int j = 0; j < 4; ++j)
                    acc[i][j] = __builtin_amdgcn_mfma_f32_16x16x32_bf16(af[i], bfb[u & 1][j], acc[i][j], 0, 0, 0);
            __builtin_amdgcn_s_setprio(0);
            #pragma unroll
            for (int i = 4; i < 8; ++i) af[i] = *(const frag8*)(LA + aOff + i * 512);
            #pragma unroll
            for (int j = 0; j < 4; ++j)
                bfb[(u + 1) & 1][j] = *(const frag8*)(LBn + bOff + j * 512);
            __builtin_amdgcn_s_setprio(1);
            #pragma unroll
            for (int i = 4; i < 8; ++i)
                #pragma unroll
                for (int j = 0; j < 4; ++j)
                    acc[i][j] = __builtin_amdgcn_mfma_f32_16x16x32_bf16(af[i], bfb[u & 1][j], acc[i][j], 0, 0, 0);
            __builtin_amdgcn_s_setprio(0);
            asm volatile("" ::: "memory");
            __builtin_amdgcn_s_barrier();
        }
    }
    asm volatile("s_waitcnt vmcnt(0)" ::: "memory");

    float* C = partial + ((size_t)zp << 18);
    #pragma unroll
    for (int i = 0; i < 8; ++i) {
        const int rg = m0 + wr * 128 + i * 16 + quad * 4;
        #pragma unroll
        for (int j = 0; j < 4; ++j) {
            const int cg = n0 + wc * 64 + j * 16 + l15;
            #pragma unroll
            for (int r = 0; r < 4; ++r)
                C[(size_t)(rg + r) * 512 + cg] = acc[i][j][r];
        }
    }
}

// ---------------- prep: weight transposes + Wc fold in one dispatch ---------------
__global__ void prep(const float* __restrict__ a_w1, const float* __restrict__ v_w1,
                     const float* __restrict__ a_w2, const float* __restrict__ v_w2,
                     const float* __restrict__ W, const float* __restrict__ v_b2,
                     unsigned short* __restrict__ aw1T, unsigned short* __restrict__ vw1T,
                     unsigned short* __restrict__ aw2T,
                     unsigned short* __restrict__ WcT, float* __restrict__ bc)
{
    const int b = blockIdx.x;
    __shared__ float tl[32][33];
    __shared__ float wcol[256];
    if (b < 320) {
        const float* src; unsigned short* dst; int R, C, tile;
        if (b < 128)      { src = a_w1; dst = aw1T; R = 512; C = 256; tile = b; }
        else if (b < 256) { src = v_w1; dst = vw1T; R = 512; C = 256; tile = b - 128; }
        else              { src = a_w2; dst = aw2T; R = 256; C = 256; tile = b - 256; }
        const int tilesX = C / 32;
        const int bx = (tile % tilesX) * 32, by = (tile / tilesX) * 32;
        const int tx = threadIdx.x & 31, ty = threadIdx.x >> 5;
        #pragma unroll
        for (int r = ty; r < 32; r += 8)
            tl[r][tx] = src[(size_t)(by + r) * C + bx + tx];
        __syncthreads();
        #pragma unroll
        for (int c = ty; c < 32; c += 8)
            dst[(size_t)(bx + c) * R + by + tx] = f2bf_r(tl[tx][c]);
    } else {
        const int n = b - 320, k = threadIdx.x;
        wcol[k] = W[(size_t)k * 256 + n];
        __syncthreads();
        float s = 0.f;
        #pragma unroll 8
        for (int d = 0; d < 256; ++d) s += v_w2[(size_t)k * 256 + d] * wcol[d];
        WcT[(size_t)n * 256 + k] = f2bf_r(s);
        if (k == 0) {
            float tt = 0.f;
            for (int d = 0; d < 256; ++d) tt += v_b2[d] * wcol[d];
            bc[n] = tt;
        }
    }
}

// split-K sum + max over deltas; sc = slices per delta
__global__ void reduce_max(const float* __restrict__ partial, float* __restrict__ out, int sc) {
    const int idx = blockIdx.x * blockDim.x + threadIdx.x;
    float best = -3.4e38f;
    for (int d = 0; d < 9; ++d) {
        float ssum = 0.f;
        const float* p = partial + ((size_t)(d * sc) << 18) + idx;
        for (int k = 0; k < sc; ++k) ssum += p[(size_t)k << 18];
        best = fmaxf(best, ssum);
    }
    out[idx] = best;
}

extern "C" void kernel_launch(void* const* d_in, const int* in_sizes, int n_in,
                              void* d_out, int out_size, void* d_ws, size_t ws_size,
                              hipStream_t stream) {
    const float* audio = (const float*)d_in[0];
    const float* video = (const float*)d_in[1];
    const float* a_w1  = (const float*)d_in[2];
    const float* a_b1  = (const float*)d_in[3];
    const float* a_w2  = (const float*)d_in[4];
    const float* a_b2  = (const float*)d_in[5];
    const float* v_w1  = (const float*)d_in[6];
    const float* v_b1  = (const float*)d_in[7];
    const float* v_w2  = (const float*)d_in[8];
    const float* v_b2  = (const float*)d_in[9];
    const float* Wm    = (const float*)d_in[10];

    char* ws = (char*)d_ws;
    unsigned short* aw1T = (unsigned short*)(ws + 0);          // [256][512]
    unsigned short* vw1T = (unsigned short*)(ws + 262144);     // [256][512]
    unsigned short* aw2T = (unsigned short*)(ws + 524288);     // [256][256]
    unsigned short* WcT  = (unsigned short*)(ws + 655360);     // [256][256]
    float*          bc   = (float*)(ws + 786432);              // [256]
    unsigned short* a_bf = (unsigned short*)(ws + 1048576);    // [512][32768] bf16
    unsigned short* pv   = (unsigned short*)(ws + 34603008);   // [512][32768] bf16
    float* partial       = (float*)(ws + 68157440);            // [9*sc][512][512] fp32
    float* out = (float*)d_out;

    // sc=7 partial needs ws through 128 MiB; fall back to 36-slice footprint if less.
    const int sc = (ws_size >= 134217728ull) ? 7 : 4;

    // 1: weight prep
    prep<<<dim3(576), 256, 0, stream>>>(a_w1, v_w1, a_w2, v_w2, Wm, v_b2,
                                        aw1T, vw1T, aw2T, WcT, bc);
    // 2: fused two-layer MLP, both modalities (h never leaves LDS)
    mlp_fused<<<dim3(1024, 2), 256, 0, stream>>>(
        audio, video, aw1T, vw1T, a_b1, v_b1, aw2T, WcT, a_b2, bc, a_bf, pv);
    // 3: lag correlation
    if (sc == 7)
        gemm_corr_b<<<dim3(4, 2, 63), 512, 0, stream>>>(a_bf, pv, partial);
    else
        gemm_corr<<<dim3(2, 2, 36), 512, 0, stream>>>(a_bf, pv, partial, 4);
    // 4: split-K sum + max over deltas
    reduce_max<<<dim3(1024), 256, 0, stream>>>(partial, out, sc);
}

// Round 10
// 494.335 us; speedup vs baseline: 1.0160x; 1.0160x over previous
//
#include <hip/hip_runtime.h>
#include <cstdint>
#include <cstddef>

typedef __attribute__((ext_vector_type(8))) short frag8;
typedef __attribute__((ext_vector_type(4))) float f32x4;

static __device__ __forceinline__ unsigned short f2bf_r(float f) {
    return (unsigned short)((__float_as_uint(f) + 0x8000u) >> 16);   // round-half-up
}

// async global->LDS, 16B per lane. LDS dest = wave-uniform base + lane*16.
static __device__ __forceinline__ void gll16(const void* g, void* l) {
    __builtin_amdgcn_global_load_lds(
        (const __attribute__((address_space(1))) unsigned int*)g,
        (__attribute__((address_space(3))) unsigned int*)l, 16, 0, 0);
}

// ---------------- fused MLP: out = relu(X@W1+b1)@W2' + b2' ----------------------
// R1 version verbatim (replay-proven 5x).
__global__ __launch_bounds__(256, 2)
void mlp_fused(const float* __restrict__ X0, const float* __restrict__ X1,
               const unsigned short* __restrict__ W1T0, const unsigned short* __restrict__ W1T1,
               const float* __restrict__ b1v0, const float* __restrict__ b1v1,
               const unsigned short* __restrict__ W2T0, const unsigned short* __restrict__ W2T1,
               const float* __restrict__ b2v0, const float* __restrict__ b2v1,
               unsigned short* __restrict__ O0, unsigned short* __restrict__ O1)
{
    __shared__ __align__(16) unsigned short As[64 * 72];     // 9216 B (fp32-staged A, pad 72)
    __shared__ __align__(16) unsigned short Bs[256 * 64];    // 32768 B (weight tile, swizzled)
    __shared__ __align__(16) unsigned short hs[64 * 264];    // 33792 B (h tile / C-stage)

    const int mod = blockIdx.y;
    const float* X = mod ? X1 : X0;
    const unsigned short* W1T = mod ? W1T1 : W1T0;
    const unsigned short* W2T = mod ? W2T1 : W2T0;
    const float* b1 = mod ? b1v1 : b1v0;
    const float* b2 = mod ? b2v1 : b2v0;
    unsigned short* O = mod ? O1 : O0;

    const int t    = threadIdx.x;
    const int wave = t >> 6;
    const int lane = t & 63;
    const int quad = lane >> 4;
    const int l15  = lane & 15;
    const int m0   = blockIdx.x * 64;

    const int rowB = lane >> 3;                 // 0..7
    const int qB   = (lane & 7) ^ rowB;
    const int nRowBase = wave * 64 + rowB;      // +p*8 per call
    unsigned short* BsW = Bs + wave * 4096;     // 8 calls x 512 ush
    const int swz = l15 & 7;

    f32x4 acc[4][4];
    #pragma unroll
    for (int i = 0; i < 4; ++i)
        #pragma unroll
        for (int j = 0; j < 4; ++j)
            acc[i][j] = (f32x4){0.f, 0.f, 0.f, 0.f};

    // ---------------- phase 1: h = relu(X@W1+b1), K=512, BK=64 ----------------
    for (int k0 = 0; k0 < 512; k0 += 64) {
        #pragma unroll
        for (int p = 0; p < 4; ++p) {           // stage A 64x64 fp32 -> bf16
            const int idx = p * 256 + t;
            const int row = idx >> 4;
            const int col = (idx & 15) * 4;
            const float4 v = *(const float4*)(X + (size_t)(m0 + row) * 512 + k0 + col);
            const unsigned int a0 = __float_as_uint(v.x) + 0x8000u;
            const unsigned int a1 = __float_as_uint(v.y) + 0x8000u;
            const unsigned int a2 = __float_as_uint(v.z) + 0x8000u;
            const unsigned int a3 = __float_as_uint(v.w) + 0x8000u;
            uint2 pk;
            pk.x = __builtin_amdgcn_perm(a1, a0, 0x07060302u);
            pk.y = __builtin_amdgcn_perm(a3, a2, 0x07060302u);
            *(uint2*)&As[row * 72 + col] = pk;
        }
        #pragma unroll
        for (int p = 0; p < 8; ++p)             // stage W1T 256x64 bf16
            gll16(W1T + (size_t)(nRowBase + p * 8) * 512 + qB * 8 + k0, BsW + p * 512);
        __syncthreads();

        frag8 af[2][4], bf[2][4];
        #pragma unroll
        for (int i = 0; i < 4; ++i)
            #pragma unroll
            for (int kh = 0; kh < 2; ++kh)
                af[kh][i] = *(const frag8*)&As[(i * 16 + l15) * 72 + kh * 32 + quad * 8];
        #pragma unroll
        for (int j = 0; j < 4; ++j) {
            const int row = wave * 64 + j * 16 + l15;
            #pragma unroll
            for (int kh = 0; kh < 2; ++kh)
                bf[kh][j] = *(const frag8*)&Bs[row * 64 + (((kh * 4 + quad) ^ swz) * 8)];
        }
        #pragma unroll
        for (int kh = 0; kh < 2; ++kh)
            #pragma unroll
            for (int i = 0; i < 4; ++i)
                #pragma unroll
                for (int j = 0; j < 4; ++j)
                    acc[i][j] = __builtin_amdgcn_mfma_f32_16x16x32_bf16(af[kh][i], bf[kh][j], acc[i][j], 0, 0, 0);
        __syncthreads();
    }

    // h -> LDS (bias + relu + bf16), C-layout scatter
    #pragma unroll
    for (int j = 0; j < 4; ++j) {
        const int col = wave * 64 + j * 16 + l15;
        const float bv = b1[col];
        #pragma unroll
        for (int i = 0; i < 4; ++i) {
            const int rl = i * 16 + quad * 4;
            #pragma unroll
            for (int r = 0; r < 4; ++r)
                hs[(rl + r) * 264 + col] = f2bf_r(fmaxf(acc[i][j][r] + bv, 0.0f));
        }
    }
    __syncthreads();

    // ---------------- phase 2: out = h@W2' + b2', K=256, BK=64 ----------------
    #pragma unroll
    for (int i = 0; i < 4; ++i)
        #pragma unroll
        for (int j = 0; j < 4; ++j)
            acc[i][j] = (f32x4){0.f, 0.f, 0.f, 0.f};

    for (int k0 = 0; k0 < 256; k0 += 64) {
        #pragma unroll
        for (int p = 0; p < 8; ++p)
            gll16(W2T + (size_t)(nRowBase + p * 8) * 256 + qB * 8 + k0, BsW + p * 512);
        __syncthreads();

        frag8 af[2][4], bf[2][4];
        #pragma unroll
        for (int i = 0; i < 4; ++i)
            #pragma unroll
            for (int kh = 0; kh < 2; ++kh)
                af[kh][i] = *(const frag8*)&hs[(i * 16 + l15) * 264 + k0 + kh * 32 + quad * 8];
        #pragma unroll
        for (int j = 0; j < 4; ++j) {
            const int row = wave * 64 + j * 16 + l15;
            #pragma unroll
            for (int kh = 0; kh < 2; ++kh)
                bf[kh][j] = *(const frag8*)&Bs[row * 64 + (((kh * 4 + quad) ^ swz) * 8)];
        }
        #pragma unroll
        for (int kh = 0; kh < 2; ++kh)
            #pragma unroll
            for (int i = 0; i < 4; ++i)
                #pragma unroll
                for (int j = 0; j < 4; ++j)
                    acc[i][j] = __builtin_amdgcn_mfma_f32_16x16x32_bf16(af[kh][i], bf[kh][j], acc[i][j], 0, 0, 0);
        __syncthreads();
    }

    // out epilogue: bias + bf16 -> hs C-stage -> coalesced 16B stores
    #pragma unroll
    for (int j = 0; j < 4; ++j) {
        const int col = wave * 64 + j * 16 + l15;
        const float bv = b2[col];
        #pragma unroll
        for (int i = 0; i < 4; ++i) {
            const int rl = i * 16 + quad * 4;
            #pragma unroll
            for (int r = 0; r < 4; ++r)
                hs[(rl + r) * 264 + col] = f2bf_r(acc[i][j][r] + bv);
        }
    }
    __syncthreads();
    #pragma unroll
    for (int u = 0; u < 8; ++u) {
        const int chunk = u * 256 + t;          // 0..2047 16B chunks
        const int row = chunk >> 5;
        const int c16 = (chunk & 31) * 8;
        uint4 v = *(const uint4*)&hs[row * 264 + c16];
        *(uint4*)&O[(size_t)(m0 + row) * 256 + c16] = v;
    }
}

// ---------------- lag correlation GEMM v6: full cross-tile read hoist -------------
// R8's 4-slot ring skeleton VERBATIM (stage t+3, vmcnt(8), barrier, ..., barrier;
// never drains mid-loop) — only the ds_read placement changes. R9 falsified
// cross-block overlap; the serial-sum model says the gate is: every tile's MFMA
// waits on reads issued after the same barrier (compiler can't hoist ds_read past
// s_barrier). Fix: hoist ALL of tile t+1's MFMA1 inputs to body t.
//   body t: [stage t+3][vmcnt(8): tiles t,t+1 landed][barrier]
//           issue afB(t) (4 reads, slot t&3)                 — drains under MFMA1
//           prefetch afA/bf of t+1 (8 reads, slot (t+1)&3)   — used at body t+1
//           MFMA1 (uses afA/bf parity t&1, read at body t-1: ZERO lgkm dep)
//           MFMA2 (waits afB only — first in lgkm queue, hidden by MFMA1)
//           [barrier]
// Ledger (extends R5's hardware-proven bf-prefetch): prefetch slot (t+1)&3 is
// landed (vmcnt(8)) + cross-wave visible (barrier); WAR vs stage of tile t+5 into
// the same slot at body t+2: reads retire before body t+1's MFMA use < body t+1's
// closing barrier < body t+2's stage. Register audit (R4 lesson): frags 80 VGPR
// (afA 2x16 + bf 2x16 + afB 16) + addr ~45 = ~125 VGPR + acc 128 AGPR <= 256.
__global__ __launch_bounds__(512, 2)
void gemm_corr(const unsigned short* __restrict__ A, const unsigned short* __restrict__ B,
               float* __restrict__ partial, int sc)
{
    __shared__ __align__(16) unsigned short lds[4 * 2 * 8192];  // 4 slots x (A,B) x 16 KiB

    const int t    = threadIdx.x;
    const int wave = t >> 6;
    const int lane = t & 63;
    const int quad = lane >> 4;
    const int l15  = lane & 15;
    const int wr   = wave >> 2;          // 0..1  (M half)
    const int wc   = wave & 3;           // 0..3  (N quarter)

    // T1 block-id de-swizzle (bijective, m204). logical ell = ((s*9 + d)*2 + y)*2 + x
    const int L = blockIdx.x + (blockIdx.y << 1) + (blockIdx.z << 2);
    int ell;
    if (sc == 7) {                       // 252 blocks: chunks {32,32,32,32,31,31,31,31}
        const int xcd = L & 7, off = L >> 3;
        ell = (xcd < 4 ? xcd * 32 : 128 + (xcd - 4) * 31) + off;
    } else {                             // 144 blocks: 18 per chunk
        const int xcd = L & 7, off = L >> 3;
        ell = xcd * 18 + off;
    }
    const int bx   = ell & 1;
    const int by   = (ell >> 1) & 1;
    const int rest = ell >> 2;           // [0, 9*sc)
    const int d    = rest % 9;
    const int s    = rest / 9;
    const int m0   = by * 256;
    const int n0   = bx * 256;

    int t0, nT;
    if (sc == 7) { nT = (s == 6) ? 136 : 148; t0 = s * 148; }
    else         { nT = 256;                  t0 = s << 8; }
    const int zp     = d * sc + s;       // partial slice index (matches reduce_max)
    const int delta  = d - 4;
    const int kStart = t0 * 32;
    const int koff   = (32768 - 256 * delta) & 32767;   // b index k+koff == k - 256*delta (mod 32768)

    // staging source mapping: LDS gets linear lane*16; global src granule pre-swizzled
    // so that LDS(rp, g) holds src granule g ^ (rp&7).
    const int gsrc      = (lane & 7) ^ ((lane >> 3) & 7);
    const int srcRowOff = ((lane >> 3) << 1) + (gsrc >> 2);
    const int srcCol    = (gsrc & 3) << 3;
    const size_t aSrcBase = (size_t)(m0 + srcRowOff) * 32768 + srcCol;
    const size_t bSrcBase = (size_t)(n0 + srcRowOff) * 32768 + srcCol;

    // ds_read offsets (in shorts): frag row r -> rp=r>>1, g_log=(r&1)*4+quad,
    // phys granule g_log ^ (rp&7). i/j stride = 1024 B = 512 shorts.
    const int gphys = (((l15 & 1) << 2) | quad) ^ ((l15 >> 1) & 7);
    const int aOff  = (wr * 64 + (l15 >> 1)) * 64 + gphys * 8;
    const int bOff  = (wc * 32 + (l15 >> 1)) * 64 + gphys * 8;

    f32x4 acc[8][4];
    #pragma unroll
    for (int i = 0; i < 8; ++i)
        #pragma unroll
        for (int j = 0; j < 4; ++j)
            acc[i][j] = (f32x4){0.f, 0.f, 0.f, 0.f};

    frag8 afA[2][4], bfb[2][4];          // cross-tile double-buffered MFMA1 inputs

    // prologue: stage tiles 0,1,2 into slots 0,1,2 (4 glls per wave per tile)
    #pragma unroll
    for (int pt = 0; pt < 3; ++pt) {
        const int kk = (kStart + pt * 32) & 32767;
        const int kb = (kk + koff) & 32767;
        #pragma unroll
        for (int qq = 0; qq < 2; ++qq) {
            const int c = wave * 2 + qq;        // 16-row chunk, 1 KiB each
            gll16(A + aSrcBase + (size_t)c * 16 * 32768 + kk, &lds[pt * 16384 + c * 512]);
            gll16(B + bSrcBase + (size_t)c * 16 * 32768 + kb, &lds[pt * 16384 + 8192 + c * 512]);
        }
    }
    // 12 outstanding; <=8 retires tile 0 -> landed own-wave; barrier -> visible.
    asm volatile("s_waitcnt vmcnt(8)" ::: "memory");
    __builtin_amdgcn_s_barrier();
    asm volatile("" ::: "memory");
    #pragma unroll
    for (int i = 0; i < 4; ++i)          // preload tile 0's MFMA1 inputs (parity 0)
        afA[0][i] = *(const frag8*)(&lds[0] + aOff + i * 512);
    #pragma unroll
    for (int j = 0; j < 4; ++j)
        bfb[0][j] = *(const frag8*)(&lds[8192] + bOff + j * 512);

    for (int kt0 = 0; kt0 < nT; kt0 += 2) {     // nT is always even
        #pragma unroll
        for (int u = 0; u < 2; ++u) {           // parity u = tile&1
            const int ti = kt0 + u;             // current tile index (slot ti&3)
            // stage tile ti+3 into slot (ti+3)&3 (its old tile ti-1 was consumed
            // before the previous body's closing barrier).
            {
                const int kk = (kStart + (ti + 3) * 32) & 32767;
                const int kb = (kk + koff) & 32767;
                unsigned short* LSa = &lds[((ti + 3) & 3) * 16384 + wave * 1024];
                unsigned short* LSb = LSa + 8192;
                #pragma unroll
                for (int qq = 0; qq < 2; ++qq) {
                    const int c = wave * 2 + qq;
                    gll16(A + aSrcBase + (size_t)c * 16 * 32768 + kk, LSa + qq * 512);
                    gll16(B + bSrcBase + (size_t)c * 16 * 32768 + kb, LSb + qq * 512);
                }
            }
            // 16 outstanding (tiles ti..ti+3); <=8 => tiles ti AND ti+1 landed.
            asm volatile("s_waitcnt vmcnt(8)" ::: "memory");
            __builtin_amdgcn_s_barrier();       // cross-wave visibility of DMA writes
            asm volatile("" ::: "memory");

            const unsigned short* LA  = &lds[(ti & 3) * 16384];
            const unsigned short* LAn = &lds[((ti + 1) & 3) * 16384];   // tile ti+1
            const unsigned short* LBn = LAn + 8192;

            frag8 afB[4];
            #pragma unroll                      // afB(ti): FIRST in lgkm queue
            for (int i = 0; i < 4; ++i) afB[i] = *(const frag8*)(LA + aOff + (i + 4) * 512);
            #pragma unroll                      // prefetch tile ti+1 MFMA1 inputs
            for (int i = 0; i < 4; ++i) afA[u ^ 1][i] = *(const frag8*)(LAn + aOff + i * 512);
            #pragma unroll
            for (int j = 0; j < 4; ++j) bfb[u ^ 1][j] = *(const frag8*)(LBn + bOff + j * 512);

            __builtin_amdgcn_s_setprio(1);
            #pragma unroll                      // MFMA1: parity-u regs, zero lgkm dep
            for (int i = 0; i < 4; ++i)
                #pragma unroll
                for (int j = 0; j < 4; ++j)
                    acc[i][j] = __builtin_amdgcn_mfma_f32_16x16x32_bf16(afA[u][i], bfb[u][j], acc[i][j], 0, 0, 0);
            __builtin_amdgcn_s_setprio(0);
            // MFMA2 waits afB only (lgkmcnt(8): 8 prefetch reads stay in flight)
            __builtin_amdgcn_s_setprio(1);
            #pragma unroll
            for (int i = 0; i < 4; ++i)
                #pragma unroll
                for (int j = 0; j < 4; ++j)
                    acc[i + 4][j] = __builtin_amdgcn_mfma_f32_16x16x32_bf16(afB[i], bfb[u][j], acc[i + 4][j], 0, 0, 0);
            __builtin_amdgcn_s_setprio(0);
            asm volatile("" ::: "memory");
            __builtin_amdgcn_s_barrier();       // protect this tile's reads from next stage
        }
    }
    // drain dangling prefetch DMAs before endpgm (LDS gets reassigned to next block)
    asm volatile("s_waitcnt vmcnt(0)" ::: "memory");

    float* C = partial + ((size_t)zp << 18);
    #pragma unroll
    for (int i = 0; i < 8; ++i) {
        const int rg = m0 + wr * 128 + i * 16 + quad * 4;
        #pragma unroll
        for (int j = 0; j < 4; ++j) {
            const int cg = n0 + wc * 64 + j * 16 + l15;
            #pragma unroll
            for (int r = 0; r < 4; ++r)
                C[(size_t)(rg + r) * 512 + cg] = acc[i][j][r];
        }
    }
}

// ---------------- prep: weight transposes + Wc fold in one dispatch ---------------
__global__ void prep(const float* __restrict__ a_w1, const float* __restrict__ v_w1,
                     const float* __restrict__ a_w2, const float* __restrict__ v_w2,
                     const float* __restrict__ W, const float* __restrict__ v_b2,
                     unsigned short* __restrict__ aw1T, unsigned short* __restrict__ vw1T,
                     unsigned short* __restrict__ aw2T,
                     unsigned short* __restrict__ WcT, float* __restrict__ bc)
{
    const int b = blockIdx.x;
    __shared__ float tl[32][33];
    __shared__ float wcol[256];
    if (b < 320) {
        const float* src; unsigned short* dst; int R, C, tile;
        if (b < 128)      { src = a_w1; dst = aw1T; R = 512; C = 256; tile = b; }
        else if (b < 256) { src = v_w1; dst = vw1T; R = 512; C = 256; tile = b - 128; }
        else              { src = a_w2; dst = aw2T; R = 256; C = 256; tile = b - 256; }
        const int tilesX = C / 32;
        const int bx = (tile % tilesX) * 32, by = (tile / tilesX) * 32;
        const int tx = threadIdx.x & 31, ty = threadIdx.x >> 5;
        #pragma unroll
        for (int r = ty; r < 32; r += 8)
            tl[r][tx] = src[(size_t)(by + r) * C + bx + tx];
        __syncthreads();
        #pragma unroll
        for (int c = ty; c < 32; c += 8)
            dst[(size_t)(bx + c) * R + by + tx] = f2bf_r(tl[tx][c]);
    } else {
        const int n = b - 320, k = threadIdx.x;
        wcol[k] = W[(size_t)k * 256 + n];
        __syncthreads();
        float s = 0.f;
        #pragma unroll 8
        for (int d = 0; d < 256; ++d) s += v_w2[(size_t)k * 256 + d] * wcol[d];
        WcT[(size_t)n * 256 + k] = f2bf_r(s);
        if (k == 0) {
            float tt = 0.f;
            for (int d = 0; d < 256; ++d) tt += v_b2[d] * wcol[d];
            bc[n] = tt;
        }
    }
}

// split-K sum + max over deltas; sc = slices per delta
__global__ void reduce_max(const float* __restrict__ partial, float* __restrict__ out, int sc) {
    const int idx = blockIdx.x * blockDim.x + threadIdx.x;
    float best = -3.4e38f;
    for (int d = 0; d < 9; ++d) {
        float ssum = 0.f;
        const float* p = partial + ((size_t)(d * sc) << 18) + idx;
        for (int k = 0; k < sc; ++k) ssum += p[(size_t)k << 18];
        best = fmaxf(best, ssum);
    }
    out[idx] = best;
}

extern "C" void kernel_launch(void* const* d_in, const int* in_sizes, int n_in,
                              void* d_out, int out_size, void* d_ws, size_t ws_size,
                              hipStream_t stream) {
    const float* audio = (const float*)d_in[0];
    const float* video = (const float*)d_in[1];
    const float* a_w1  = (const float*)d_in[2];
    const float* a_b1  = (const float*)d_in[3];
    const float* a_w2  = (const float*)d_in[4];
    const float* a_b2  = (const float*)d_in[5];
    const float* v_w1  = (const float*)d_in[6];
    const float* v_b1  = (const float*)d_in[7];
    const float* v_w2  = (const float*)d_in[8];
    const float* v_b2  = (const float*)d_in[9];
    const float* Wm    = (const float*)d_in[10];

    char* ws = (char*)d_ws;
    unsigned short* aw1T = (unsigned short*)(ws + 0);          // [256][512]
    unsigned short* vw1T = (unsigned short*)(ws + 262144);     // [256][512]
    unsigned short* aw2T = (unsigned short*)(ws + 524288);     // [256][256]
    unsigned short* WcT  = (unsigned short*)(ws + 655360);     // [256][256]
    float*          bc   = (float*)(ws + 786432);              // [256]
    unsigned short* a_bf = (unsigned short*)(ws + 1048576);    // [512][32768] bf16
    unsigned short* pv   = (unsigned short*)(ws + 34603008);   // [512][32768] bf16
    float* partial       = (float*)(ws + 68157440);            // [9*sc][512][512] fp32
    float* out = (float*)d_out;

    // split-K=7 per delta needs partial end at exactly 128 MiB of workspace;
    // fall back to the 36-slice footprint if ws is smaller.
    const int sc = (ws_size >= 134217728ull) ? 7 : 4;

    // 1: weight prep
    prep<<<dim3(576), 256, 0, stream>>>(a_w1, v_w1, a_w2, v_w2, Wm, v_b2,
                                        aw1T, vw1T, aw2T, WcT, bc);
    // 2: fused two-layer MLP, both modalities (h never leaves LDS)
    mlp_fused<<<dim3(1024, 2), 256, 0, stream>>>(
        audio, video, aw1T, vw1T, a_b1, v_b1, aw2T, WcT, a_b2, bc, a_bf, pv);
    // 3: lag correlation (256^2 tiles, 4-slot ring + full cross-tile read hoist)
    gemm_corr<<<dim3(2, 2, 9 * sc), 512, 0, stream>>>(a_bf, pv, partial, sc);
    // 4: split-K sum + max over deltas
    reduce_max<<<dim3(1024), 256, 0, stream>>>(partial, out, sc);
}

// Round 11
// 484.303 us; speedup vs baseline: 1.0370x; 1.0207x over previous
//
#include <hip/hip_runtime.h>
#include <cstdint>
#include <cstddef>

typedef __attribute__((ext_vector_type(8))) short frag8;
typedef __attribute__((ext_vector_type(4))) float f32x4;

static __device__ __forceinline__ unsigned short f2bf_r(float f) {
    return (unsigned short)((__float_as_uint(f) + 0x8000u) >> 16);   // round-half-up
}

// async global->LDS, 16B per lane. LDS dest = wave-uniform base + lane*16.
static __device__ __forceinline__ void gll16(const void* g, void* l) {
    __builtin_amdgcn_global_load_lds(
        (const __attribute__((address_space(1))) unsigned int*)g,
        (__attribute__((address_space(3))) unsigned int*)l, 16, 0, 0);
}

// ---------------- fused MLP: out = relu(X@W1+b1)@W2' + b2' ----------------------
// X fp32 [65536][512]; W1T bf16 [256][512]; W2T bf16 [256][256]; out bf16 [65536][256].
// Block: 64 M-rows x full N=256. h tile lives in LDS (never hits HBM).
// blockIdx.y selects modality (0=audio, 1=video w/ W2@W fold).
// R1 version verbatim (replay-proven 5x; both pipelining variants neutral/negative).
__global__ __launch_bounds__(256, 2)
void mlp_fused(const float* __restrict__ X0, const float* __restrict__ X1,
               const unsigned short* __restrict__ W1T0, const unsigned short* __restrict__ W1T1,
               const float* __restrict__ b1v0, const float* __restrict__ b1v1,
               const unsigned short* __restrict__ W2T0, const unsigned short* __restrict__ W2T1,
               const float* __restrict__ b2v0, const float* __restrict__ b2v1,
               unsigned short* __restrict__ O0, unsigned short* __restrict__ O1)
{
    __shared__ __align__(16) unsigned short As[64 * 72];     // 9216 B (fp32-staged A, pad 72)
    __shared__ __align__(16) unsigned short Bs[256 * 64];    // 32768 B (weight tile, swizzled)
    __shared__ __align__(16) unsigned short hs[64 * 264];    // 33792 B (h tile / C-stage)

    const int mod = blockIdx.y;
    const float* X = mod ? X1 : X0;
    const unsigned short* W1T = mod ? W1T1 : W1T0;
    const unsigned short* W2T = mod ? W2T1 : W2T0;
    const float* b1 = mod ? b1v1 : b1v0;
    const float* b2 = mod ? b2v1 : b2v0;
    unsigned short* O = mod ? O1 : O0;

    const int t    = threadIdx.x;
    const int wave = t >> 6;
    const int lane = t & 63;
    const int quad = lane >> 4;
    const int l15  = lane & 15;
    const int m0   = blockIdx.x * 64;

    // gll B mapping (8 granules/row, xor-swizzle: stored g holds src g ^ (row&7))
    const int rowB = lane >> 3;                 // 0..7
    const int qB   = (lane & 7) ^ rowB;
    const int nRowBase = wave * 64 + rowB;      // +p*8 per call
    unsigned short* BsW = Bs + wave * 4096;     // 8 calls x 512 ush
    const int swz = l15 & 7;

    f32x4 acc[4][4];
    #pragma unroll
    for (int i = 0; i < 4; ++i)
        #pragma unroll
        for (int j = 0; j < 4; ++j)
            acc[i][j] = (f32x4){0.f, 0.f, 0.f, 0.f};

    // ---------------- phase 1: h = relu(X@W1+b1), K=512, BK=64 ----------------
    for (int k0 = 0; k0 < 512; k0 += 64) {
        #pragma unroll
        for (int p = 0; p < 4; ++p) {           // stage A 64x64 fp32 -> bf16
            const int idx = p * 256 + t;
            const int row = idx >> 4;
            const int col = (idx & 15) * 4;
            const float4 v = *(const float4*)(X + (size_t)(m0 + row) * 512 + k0 + col);
            const unsigned int a0 = __float_as_uint(v.x) + 0x8000u;
            const unsigned int a1 = __float_as_uint(v.y) + 0x8000u;
            const unsigned int a2 = __float_as_uint(v.z) + 0x8000u;
            const unsigned int a3 = __float_as_uint(v.w) + 0x8000u;
            uint2 pk;
            pk.x = __builtin_amdgcn_perm(a1, a0, 0x07060302u);
            pk.y = __builtin_amdgcn_perm(a3, a2, 0x07060302u);
            *(uint2*)&As[row * 72 + col] = pk;
        }
        #pragma unroll
        for (int p = 0; p < 8; ++p)             // stage W1T 256x64 bf16
            gll16(W1T + (size_t)(nRowBase + p * 8) * 512 + qB * 8 + k0, BsW + p * 512);
        __syncthreads();

        frag8 af[2][4], bf[2][4];
        #pragma unroll
        for (int i = 0; i < 4; ++i)
            #pragma unroll
            for (int kh = 0; kh < 2; ++kh)
                af[kh][i] = *(const frag8*)&As[(i * 16 + l15) * 72 + kh * 32 + quad * 8];
        #pragma unroll
        for (int j = 0; j < 4; ++j) {
            const int row = wave * 64 + j * 16 + l15;
            #pragma unroll
            for (int kh = 0; kh < 2; ++kh)
                bf[kh][j] = *(const frag8*)&Bs[row * 64 + (((kh * 4 + quad) ^ swz) * 8)];
        }
        #pragma unroll
        for (int kh = 0; kh < 2; ++kh)
            #pragma unroll
            for (int i = 0; i < 4; ++i)
                #pragma unroll
                for (int j = 0; j < 4; ++j)
                    acc[i][j] = __builtin_amdgcn_mfma_f32_16x16x32_bf16(af[kh][i], bf[kh][j], acc[i][j], 0, 0, 0);
        __syncthreads();
    }

    // h -> LDS (bias + relu + bf16), C-layout scatter
    #pragma unroll
    for (int j = 0; j < 4; ++j) {
        const int col = wave * 64 + j * 16 + l15;
        const float bv = b1[col];
        #pragma unroll
        for (int i = 0; i < 4; ++i) {
            const int rl = i * 16 + quad * 4;
            #pragma unroll
            for (int r = 0; r < 4; ++r)
                hs[(rl + r) * 264 + col] = f2bf_r(fmaxf(acc[i][j][r] + bv, 0.0f));
        }
    }
    __syncthreads();

    // ---------------- phase 2: out = h@W2' + b2', K=256, BK=64 ----------------
    #pragma unroll
    for (int i = 0; i < 4; ++i)
        #pragma unroll
        for (int j = 0; j < 4; ++j)
            acc[i][j] = (f32x4){0.f, 0.f, 0.f, 0.f};

    for (int k0 = 0; k0 < 256; k0 += 64) {
        #pragma unroll
        for (int p = 0; p < 8; ++p)
            gll16(W2T + (size_t)(nRowBase + p * 8) * 256 + qB * 8 + k0, BsW + p * 512);
        __syncthreads();

        frag8 af[2][4], bf[2][4];
        #pragma unroll
        for (int i = 0; i < 4; ++i)
            #pragma unroll
            for (int kh = 0; kh < 2; ++kh)
                af[kh][i] = *(const frag8*)&hs[(i * 16 + l15) * 264 + k0 + kh * 32 + quad * 8];
        #pragma unroll
        for (int j = 0; j < 4; ++j) {
            const int row = wave * 64 + j * 16 + l15;
            #pragma unroll
            for (int kh = 0; kh < 2; ++kh)
                bf[kh][j] = *(const frag8*)&Bs[row * 64 + (((kh * 4 + quad) ^ swz) * 8)];
        }
        #pragma unroll
        for (int kh = 0; kh < 2; ++kh)
            #pragma unroll
            for (int i = 0; i < 4; ++i)
                #pragma unroll
                for (int j = 0; j < 4; ++j)
                    acc[i][j] = __builtin_amdgcn_mfma_f32_16x16x32_bf16(af[kh][i], bf[kh][j], acc[i][j], 0, 0, 0);
        __syncthreads();
    }

    // out epilogue: bias + bf16 -> hs C-stage -> coalesced 16B stores
    #pragma unroll
    for (int j = 0; j < 4; ++j) {
        const int col = wave * 64 + j * 16 + l15;
        const float bv = b2[col];
        #pragma unroll
        for (int i = 0; i < 4; ++i) {
            const int rl = i * 16 + quad * 4;
            #pragma unroll
            for (int r = 0; r < 4; ++r)
                hs[(rl + r) * 264 + col] = f2bf_r(acc[i][j][r] + bv);
        }
    }
    __syncthreads();
    #pragma unroll
    for (int u = 0; u < 8; ++u) {
        const int chunk = u * 256 + t;          // 0..2047 16B chunks
        const int row = chunk >> 5;
        const int c16 = (chunk & 31) * 8;
        uint4 v = *(const uint4*)&hs[row * 264 + c16];
        *(uint4*)&O[(size_t)(m0 + row) * 256 + c16] = v;
    }
}

// ---------------- lag correlation GEMM (session-best config, R8 verbatim) ---------
// 256x256 tile, 8 waves (2Mx4N => 128x64 per wave), BK=32, 16x16x32 MFMA.
// Counted-vmcnt 4-slot ring: stage tile t+3, vmcnt(8) (tiles t,t+1 landed), barrier,
// reads, 2x16 MFMA with B-frag reg double-buffer, barrier. vmcnt never drains to 0
// mid-loop. T1 bijective XCD swizzle (FETCH 370->78 MB, verified R3).
// Scheduling variants measured null/worse (R1/R5/R7/R9/R10): gemm is pinned at
// ~151 us / 44% MfmaUtil by sub-source-level serialization within this skeleton;
// the phase-split that breaks it (m201) raced on hardware (R2) and is not shipped.
__global__ __launch_bounds__(512, 2)
void gemm_corr(const unsigned short* __restrict__ A, const unsigned short* __restrict__ B,
               float* __restrict__ partial, int sc)
{
    __shared__ __align__(16) unsigned short lds[4 * 2 * 8192];  // 4 slots x (A,B) x 16 KiB

    const int t    = threadIdx.x;
    const int wave = t >> 6;
    const int lane = t & 63;
    const int quad = lane >> 4;
    const int l15  = lane & 15;
    const int wr   = wave >> 2;          // 0..1  (M half)
    const int wc   = wave & 3;           // 0..3  (N quarter)

    // T1 block-id de-swizzle (bijective, m204). logical ell = ((s*9 + d)*2 + y)*2 + x
    const int L = blockIdx.x + (blockIdx.y << 1) + (blockIdx.z << 2);
    int ell;
    if (sc == 7) {                       // 252 blocks: chunks {32,32,32,32,31,31,31,31}
        const int xcd = L & 7, off = L >> 3;
        ell = (xcd < 4 ? xcd * 32 : 128 + (xcd - 4) * 31) + off;
    } else {                             // 144 blocks: 18 per chunk
        const int xcd = L & 7, off = L >> 3;
        ell = xcd * 18 + off;
    }
    const int bx   = ell & 1;
    const int by   = (ell >> 1) & 1;
    const int rest = ell >> 2;           // [0, 9*sc)
    const int d    = rest % 9;
    const int s    = rest / 9;
    const int m0   = by * 256;
    const int n0   = bx * 256;

    int t0, nT;
    if (sc == 7) { nT = (s == 6) ? 136 : 148; t0 = s * 148; }
    else         { nT = 256;                  t0 = s << 8; }
    const int zp     = d * sc + s;       // partial slice index (matches reduce_max)
    const int delta  = d - 4;
    const int kStart = t0 * 32;
    const int koff   = (32768 - 256 * delta) & 32767;   // b index k+koff == k - 256*delta (mod 32768)

    // staging source mapping: LDS gets linear lane*16; global src granule pre-swizzled
    // so that LDS(rp, g) holds src granule g ^ (rp&7).
    const int gsrc      = (lane & 7) ^ ((lane >> 3) & 7);
    const int srcRowOff = ((lane >> 3) << 1) + (gsrc >> 2);
    const int srcCol    = (gsrc & 3) << 3;
    const size_t aSrcBase = (size_t)(m0 + srcRowOff) * 32768 + srcCol;
    const size_t bSrcBase = (size_t)(n0 + srcRowOff) * 32768 + srcCol;

    // ds_read offsets (in shorts): frag row r -> rp=r>>1, g_log=(r&1)*4+quad,
    // phys granule g_log ^ (rp&7). i/j stride = 1024 B = 512 shorts.
    const int gphys = (((l15 & 1) << 2) | quad) ^ ((l15 >> 1) & 7);
    const int aOff  = (wr * 64 + (l15 >> 1)) * 64 + gphys * 8;
    const int bOff  = (wc * 32 + (l15 >> 1)) * 64 + gphys * 8;

    f32x4 acc[8][4];
    #pragma unroll
    for (int i = 0; i < 8; ++i)
        #pragma unroll
        for (int j = 0; j < 4; ++j)
            acc[i][j] = (f32x4){0.f, 0.f, 0.f, 0.f};

    frag8 bfb[2][4];                     // B-frag double buffer (static parity index)

    // prologue: stage tiles 0,1,2 into slots 0,1,2 (4 glls per wave per tile)
    #pragma unroll
    for (int pt = 0; pt < 3; ++pt) {
        const int kk = (kStart + pt * 32) & 32767;
        const int kb = (kk + koff) & 32767;
        #pragma unroll
        for (int qq = 0; qq < 2; ++qq) {
            const int c = wave * 2 + qq;        // 16-row chunk, 1 KiB each
            gll16(A + aSrcBase + (size_t)c * 16 * 32768 + kk, &lds[pt * 16384 + c * 512]);
            gll16(B + bSrcBase + (size_t)c * 16 * 32768 + kb, &lds[pt * 16384 + 8192 + c * 512]);
        }
    }
    // 12 outstanding; <=8 retires tile 0 -> landed own-wave; barrier -> visible.
    asm volatile("s_waitcnt vmcnt(8)" ::: "memory");
    __builtin_amdgcn_s_barrier();
    asm volatile("" ::: "memory");
    #pragma unroll
    for (int j = 0; j < 4; ++j)          // preload tile 0's B frags
        bfb[0][j] = *(const frag8*)(&lds[8192] + bOff + j * 512);

    for (int kt0 = 0; kt0 < nT; kt0 += 4) {     // nT is always a multiple of 4
        #pragma unroll
        for (int u = 0; u < 4; ++u) {
            // stage tile kt0+u+3 into slot (u+3)&3 (its old tile kt0+u-1 was
            // consumed before the previous body's closing barrier).
            // k wraps &32767: beyond-slice prefetch reads valid-but-unused data.
            {
                const int kk = (kStart + (kt0 + u + 3) * 32) & 32767;
                const int kb = (kk + koff) & 32767;
                unsigned short* LSa = &lds[((u + 3) & 3) * 16384 + wave * 1024];
                unsigned short* LSb = LSa + 8192;
                #pragma unroll
                for (int qq = 0; qq < 2; ++qq) {
                    const int c = wave * 2 + qq;
                    gll16(A + aSrcBase + (size_t)c * 16 * 32768 + kk, LSa + qq * 512);
                    gll16(B + bSrcBase + (size_t)c * 16 * 32768 + kb, LSb + qq * 512);
                }
            }
            // 16 outstanding (tiles t..t+3); <=8 => tiles t AND t+1 fully landed.
            asm volatile("s_waitcnt vmcnt(8)" ::: "memory");
            __builtin_amdgcn_s_barrier();       // cross-wave visibility of DMA writes
            asm volatile("" ::: "memory");

            const unsigned short* LA  = &lds[u * 16384];
            const unsigned short* LBn = &lds[((u + 1) & 3) * 16384 + 8192];  // tile t+1 B
            frag8 af[8];
            #pragma unroll
            for (int i = 0; i < 4; ++i) af[i] = *(const frag8*)(LA + aOff + i * 512);
            __builtin_amdgcn_s_setprio(1);
            #pragma unroll
            for (int i = 0; i < 4; ++i)
                #pragma unroll
                for (int j = 0; j < 4; ++j)
                    acc[i][j] = __builtin_amdgcn_mfma_f32_16x16x32_bf16(af[i], bfb[u & 1][j], acc[i][j], 0, 0, 0);
            __builtin_amdgcn_s_setprio(0);
            #pragma unroll
            for (int i = 4; i < 8; ++i) af[i] = *(const frag8*)(LA + aOff + i * 512);
            #pragma unroll
            for (int j = 0; j < 4; ++j)         // prefetch tile t+1 B frags
                bfb[(u + 1) & 1][j] = *(const frag8*)(LBn + bOff + j * 512);
            __builtin_amdgcn_s_setprio(1);
            #pragma unroll
            for (int i = 4; i < 8; ++i)
                #pragma unroll
                for (int j = 0; j < 4; ++j)
                    acc[i][j] = __builtin_amdgcn_mfma_f32_16x16x32_bf16(af[i], bfb[u & 1][j], acc[i][j], 0, 0, 0);
            __builtin_amdgcn_s_setprio(0);
            asm volatile("" ::: "memory");
            __builtin_amdgcn_s_barrier();       // protect this tile's reads from next stage
        }
    }
    // drain dangling prefetch DMAs before endpgm (LDS gets reassigned to next block)
    asm volatile("s_waitcnt vmcnt(0)" ::: "memory");

    float* C = partial + ((size_t)zp << 18);
    #pragma unroll
    for (int i = 0; i < 8; ++i) {
        const int rg = m0 + wr * 128 + i * 16 + quad * 4;
        #pragma unroll
        for (int j = 0; j < 4; ++j) {
            const int cg = n0 + wc * 64 + j * 16 + l15;
            #pragma unroll
            for (int r = 0; r < 4; ++r)
                C[(size_t)(rg + r) * 512 + cg] = acc[i][j][r];
        }
    }
}

// ---------------- prep: weight transposes + Wc fold in one dispatch ---------------
__global__ void prep(const float* __restrict__ a_w1, const float* __restrict__ v_w1,
                     const float* __restrict__ a_w2, const float* __restrict__ v_w2,
                     const float* __restrict__ W, const float* __restrict__ v_b2,
                     unsigned short* __restrict__ aw1T, unsigned short* __restrict__ vw1T,
                     unsigned short* __restrict__ aw2T,
                     unsigned short* __restrict__ WcT, float* __restrict__ bc)
{
    const int b = blockIdx.x;
    __shared__ float tl[32][33];
    __shared__ float wcol[256];
    if (b < 320) {
        const float* src; unsigned short* dst; int R, C, tile;
        if (b < 128)      { src = a_w1; dst = aw1T; R = 512; C = 256; tile = b; }
        else if (b < 256) { src = v_w1; dst = vw1T; R = 512; C = 256; tile = b - 128; }
        else              { src = a_w2; dst = aw2T; R = 256; C = 256; tile = b - 256; }
        const int tilesX = C / 32;
        const int bx = (tile % tilesX) * 32, by = (tile / tilesX) * 32;
        const int tx = threadIdx.x & 31, ty = threadIdx.x >> 5;
        #pragma unroll
        for (int r = ty; r < 32; r += 8)
            tl[r][tx] = src[(size_t)(by + r) * C + bx + tx];
        __syncthreads();
        #pragma unroll
        for (int c = ty; c < 32; c += 8)
            dst[(size_t)(bx + c) * R + by + tx] = f2bf_r(tl[tx][c]);
    } else {
        const int n = b - 320, k = threadIdx.x;
        wcol[k] = W[(size_t)k * 256 + n];
        __syncthreads();
        float s = 0.f;
        #pragma unroll 8
        for (int d = 0; d < 256; ++d) s += v_w2[(size_t)k * 256 + d] * wcol[d];
        WcT[(size_t)n * 256 + k] = f2bf_r(s);
        if (k == 0) {
            float tt = 0.f;
            for (int d = 0; d < 256; ++d) tt += v_b2[d] * wcol[d];
            bc[n] = tt;
        }
    }
}

// split-K sum + max over deltas; sc = slices per delta
__global__ void reduce_max(const float* __restrict__ partial, float* __restrict__ out, int sc) {
    const int idx = blockIdx.x * blockDim.x + threadIdx.x;
    float best = -3.4e38f;
    for (int d = 0; d < 9; ++d) {
        float ssum = 0.f;
        const float* p = partial + ((size_t)(d * sc) << 18) + idx;
        for (int k = 0; k < sc; ++k) ssum += p[(size_t)k << 18];
        best = fmaxf(best, ssum);
    }
    out[idx] = best;
}

extern "C" void kernel_launch(void* const* d_in, const int* in_sizes, int n_in,
                              void* d_out, int out_size, void* d_ws, size_t ws_size,
                              hipStream_t stream) {
    const float* audio = (const float*)d_in[0];
    const float* video = (const float*)d_in[1];
    const float* a_w1  = (const float*)d_in[2];
    const float* a_b1  = (const float*)d_in[3];
    const float* a_w2  = (const float*)d_in[4];
    const float* a_b2  = (const float*)d_in[5];
    const float* v_w1  = (const float*)d_in[6];
    const float* v_b1  = (const float*)d_in[7];
    const float* v_w2  = (const float*)d_in[8];
    const float* v_b2  = (const float*)d_in[9];
    const float* Wm    = (const float*)d_in[10];

    char* ws = (char*)d_ws;
    unsigned short* aw1T = (unsigned short*)(ws + 0);          // [256][512]
    unsigned short* vw1T = (unsigned short*)(ws + 262144);     // [256][512]
    unsigned short* aw2T = (unsigned short*)(ws + 524288);     // [256][256]
    unsigned short* WcT  = (unsigned short*)(ws + 655360);     // [256][256]
    float*          bc   = (float*)(ws + 786432);              // [256]
    unsigned short* a_bf = (unsigned short*)(ws + 1048576);    // [512][32768] bf16
    unsigned short* pv   = (unsigned short*)(ws + 34603008);   // [512][32768] bf16
    float* partial       = (float*)(ws + 68157440);            // [9*sc][512][512] fp32
    float* out = (float*)d_out;

    // split-K=7 per delta needs partial end at exactly 128 MiB of workspace;
    // fall back to the 36-slice footprint if ws is smaller.
    const int sc = (ws_size >= 134217728ull) ? 7 : 4;

    // 1: weight prep
    prep<<<dim3(576), 256, 0, stream>>>(a_w1, v_w1, a_w2, v_w2, Wm, v_b2,
                                        aw1T, vw1T, aw2T, WcT, bc);
    // 2: fused two-layer MLP, both modalities (h never leaves LDS)
    mlp_fused<<<dim3(1024, 2), 256, 0, stream>>>(
        audio, video, aw1T, vw1T, a_b1, v_b1, aw2T, WcT, a_b2, bc, a_bf, pv);
    // 3: lag correlation (256^2 tiles, counted-vmcnt ring + bf reg-dbuf + XCD swizzle)
    gemm_corr<<<dim3(2, 2, 9 * sc), 512, 0, stream>>>(a_bf, pv, partial, sc);
    // 4: split-K sum + max over deltas
    reduce_max<<<dim3(1024), 256, 0, stream>>>(partial, out, sc);
}